// Round 2
// baseline (5085.265 us; speedup 1.0000x reference)
//
#include <hip/hip_runtime.h>
#include <math.h>

#define EPS 1e-6f

// ---------------------------------------------------------------------------
// Precompute kernels
// ---------------------------------------------------------------------------

__global__ __launch_bounds__(256) void k_flags(
    const int* __restrict__ row, const int* __restrict__ col,
    const int* __restrict__ is_tie, int* __restrict__ is_cpl,
    float* __restrict__ deg, int E)
{
    int e = blockIdx.x * 256 + threadIdx.x;
    if (e >= E) return;
    if (is_tie[e]) {
        int r = row[e], c = col[e];
        atomicOr(&is_cpl[r], 1);
        atomicOr(&is_cpl[c], 1);
        atomicAdd(&deg[r], 1.0f);
        atomicAdd(&deg[c], 1.0f);
    }
}

__global__ __launch_bounds__(256) void k_wraw(
    const int* __restrict__ col, const int* __restrict__ is_tie,
    const float* __restrict__ attr, const int* __restrict__ is_cpl,
    float* __restrict__ w_raw, float* __restrict__ wsum, int E)
{
    int e = blockIdx.x * 256 + threadIdx.x;
    if (e >= E) return;
    float wr = 0.f;
    int c = col[e];
    if (!is_tie[e] && is_cpl[c]) {
        float X = fabsf(attr[(long long)e * 10 + 1]);
        wr = 1.0f / sqrtf(X * X + EPS);
        atomicAdd(&wsum[c], wr);
    }
    w_raw[e] = wr;
}

__global__ __launch_bounds__(256) void k_wnorm(
    const int* __restrict__ col, const float* __restrict__ w_raw,
    const float* __restrict__ wsum, float* __restrict__ w_norm, int E)
{
    int e = blockIdx.x * 256 + threadIdx.x;
    if (e >= E) return;
    w_norm[e] = w_raw[e] / (wsum[col[e]] + EPS);
}

// ---------------------------------------------------------------------------
// Fused edge kernel: tie-edge MLP refine + m_edge scatter, OR msg (W_nn) +
// m_node scatter for weighted internal edges. One wave (64 lanes) per edge.
// ---------------------------------------------------------------------------

__global__ __launch_bounds__(256) void k_edge(
    const int* __restrict__ row, const int* __restrict__ col,
    const int* __restrict__ is_tie, const float* __restrict__ w_norm,
    const float* __restrict__ W_e1, const float* __restrict__ b_e1,
    const float* __restrict__ W_e2, const float* __restrict__ b_e2,
    const float* __restrict__ W_nn, const float* __restrict__ b_nn,
    float* __restrict__ e_out, const float* __restrict__ h_out,
    float* __restrict__ m_node, float* __restrict__ m_edge, int E)
{
    __shared__ float xs[4][192];
    __shared__ float h1s[4][128];
    int wv = threadIdx.x >> 6, lane = threadIdx.x & 63;
    long long g = (long long)blockIdx.x * 4 + wv;
    bool valid = g < E;
    int r = 0, c = 0, tie = 0;
    float wn = 0.f;
    if (valid) { r = row[g]; c = col[g]; tie = is_tie[g]; wn = w_norm[g]; }
    bool do_tie = valid && (tie != 0);
    bool do_msg = valid && (tie == 0) && (wn != 0.f);

    float* x = xs[wv];
    if (do_tie) {
        x[lane]       = e_out[g * 64 + lane];
        x[64 + lane]  = h_out[(long long)r * 64 + lane];
        x[128 + lane] = h_out[(long long)c * 64 + lane];
    } else if (do_msg) {
        x[lane]       = h_out[(long long)r * 64 + lane];
    }
    __syncthreads();

    if (do_tie) {
        float a0 = b_e1[lane], a1 = b_e1[64 + lane];
        #pragma unroll 8
        for (int k = 0; k < 192; ++k) {
            float xv = x[k];
            a0 = fmaf(xv, W_e1[k * 128 + lane], a0);
            a1 = fmaf(xv, W_e1[k * 128 + 64 + lane], a1);
        }
        h1s[wv][lane]      = fmaxf(a0, 0.f);
        h1s[wv][64 + lane] = fmaxf(a1, 0.f);
    }
    __syncthreads();

    if (do_tie) {
        const float* h1 = h1s[wv];
        float acc = b_e2[lane];
        #pragma unroll 8
        for (int k = 0; k < 128; ++k)
            acc = fmaf(h1[k], W_e2[k * 64 + lane], acc);
        float e_new = x[lane] + acc;
        e_out[g * 64 + lane] = e_new;
        atomicAdd(&m_edge[(long long)r * 64 + lane], e_new);
        atomicAdd(&m_edge[(long long)c * 64 + lane], e_new);
    } else if (do_msg) {
        float acc = b_nn[lane];
        #pragma unroll 8
        for (int k = 0; k < 64; ++k)
            acc = fmaf(x[k], W_nn[k * 64 + lane], acc);
        atomicAdd(&m_node[(long long)c * 64 + lane], acc * wn);
    }
}

// ---------------------------------------------------------------------------
// Node kernel: gate MLP + GRU cell, one wave per node
// ---------------------------------------------------------------------------

__global__ __launch_bounds__(256) void k_node(
    const int* __restrict__ is_cpl, const float* __restrict__ deg,
    const float* __restrict__ m_node, const float* __restrict__ m_edge,
    const float* __restrict__ W_g1, const float* __restrict__ b_g1,
    const float* __restrict__ W_g2, const float* __restrict__ b_g2,
    const float* __restrict__ W_ih, const float* __restrict__ b_ih,
    const float* __restrict__ W_hh, const float* __restrict__ b_hh,
    float* __restrict__ h_out, int N)
{
    __shared__ float xs[4][192];
    __shared__ float ms[4][64];
    int wv = threadIdx.x >> 6, lane = threadIdx.x & 63;
    long long n = (long long)blockIdx.x * 4 + wv;
    bool valid = n < N;
    bool cpl = false;
    float me = 0.f, mn = 0.f, hv = 0.f;
    if (valid) {
        cpl = is_cpl[n] != 0;
        float dg = fmaxf(deg[n], 1.0f);
        me = m_edge[n * 64 + lane] / dg;
        mn = m_node[n * 64 + lane];
        hv = h_out[n * 64 + lane];
        xs[wv][lane]       = me;
        xs[wv][64 + lane]  = mn;
        xs[wv][128 + lane] = hv;
    }
    __syncthreads();

    if (valid && cpl) {
        const float* x = xs[wv];
        float a = b_g1[lane];
        #pragma unroll 8
        for (int k = 0; k < 192; ++k)
            a = fmaf(x[k], W_g1[k * 64 + lane], a);
        float p = fmaxf(a, 0.f) * W_g2[lane];
        #pragma unroll
        for (int off = 32; off; off >>= 1) p += __shfl_xor(p, off);
        float gate = 1.0f / (1.0f + expf(-(p + b_g2[0])));
        ms[wv][lane] = me + gate * mn;
    }
    __syncthreads();

    if (valid && cpl) {
        const float* x = xs[wv];
        const float* m = ms[wv];
        float gr = b_ih[lane], gz = b_ih[64 + lane], gn = b_ih[128 + lane];
        float hr = b_hh[lane], hz = b_hh[64 + lane], hn = b_hh[128 + lane];
        #pragma unroll 4
        for (int k = 0; k < 64; ++k) {
            float mk = m[k], hk = x[128 + k];
            gr = fmaf(mk, W_ih[k * 192 + lane],       gr);
            gz = fmaf(mk, W_ih[k * 192 + 64 + lane],  gz);
            gn = fmaf(mk, W_ih[k * 192 + 128 + lane], gn);
            hr = fmaf(hk, W_hh[k * 192 + lane],       hr);
            hz = fmaf(hk, W_hh[k * 192 + 64 + lane],  hz);
            hn = fmaf(hk, W_hh[k * 192 + 128 + lane], hn);
        }
        float rg = 1.0f / (1.0f + expf(-(gr + hr)));
        float zg = 1.0f / (1.0f + expf(-(gz + hz)));
        float ng = tanhf(gn + rg * hn);
        h_out[n * 64 + lane] = (1.0f - zg) * ng + zg * hv;
    }
}

// ---------------------------------------------------------------------------
// Launch
// ---------------------------------------------------------------------------

extern "C" void kernel_launch(void* const* d_in, const int* in_sizes, int n_in,
                              void* d_out, int out_size, void* d_ws, size_t ws_size,
                              hipStream_t stream)
{
    const float* h      = (const float*)d_in[0];
    const float* e      = (const float*)d_in[1];
    const int*   eidx   = (const int*)d_in[2];
    const int*   is_tie = (const int*)d_in[3];
    const float* attr   = (const float*)d_in[4];
    const float* W_e1 = (const float*)d_in[5];  const float* b_e1 = (const float*)d_in[6];
    const float* W_e2 = (const float*)d_in[7];  const float* b_e2 = (const float*)d_in[8];
    const float* W_ih = (const float*)d_in[9];  const float* b_ih = (const float*)d_in[10];
    const float* W_hh = (const float*)d_in[11]; const float* b_hh = (const float*)d_in[12];
    const float* W_nn = (const float*)d_in[13]; const float* b_nn = (const float*)d_in[14];
    const float* W_g1 = (const float*)d_in[15]; const float* b_g1 = (const float*)d_in[16];
    const float* W_g2 = (const float*)d_in[17]; const float* b_g2 = (const float*)d_in[18];

    int N = in_sizes[0] / 64;
    int E = in_sizes[2] / 2;
    const int* row = eidx;
    const int* col = eidx + E;

    float* h_out = (float*)d_out;
    float* e_out = h_out + (long long)N * 64;

    // workspace layout (floats): is_cpl[N] | wsum[N] | deg[N] | w_raw[E] |
    //                            w_norm[E] | m_node[N*64] | m_edge[N*64]
    float* ws     = (float*)d_ws;
    int*   is_cpl = (int*)ws;
    float* wsum   = ws + N;
    float* deg    = ws + 2LL * N;
    float* w_raw  = ws + 3LL * N;
    float* w_norm = w_raw + E;
    float* m_node = w_norm + E;
    float* m_edge = m_node + (long long)N * 64;

    hipMemsetAsync(ws, 0, (size_t)3 * N * sizeof(float), stream);
    hipMemcpyAsync(h_out, h, (size_t)N * 64 * sizeof(float),
                   hipMemcpyDeviceToDevice, stream);
    hipMemcpyAsync(e_out, e, (size_t)E * 64 * sizeof(float),
                   hipMemcpyDeviceToDevice, stream);

    int gE = (E + 255) / 256;
    k_flags<<<gE, 256, 0, stream>>>(row, col, is_tie, is_cpl, deg, E);
    k_wraw <<<gE, 256, 0, stream>>>(col, is_tie, attr, is_cpl, w_raw, wsum, E);
    k_wnorm<<<gE, 256, 0, stream>>>(col, w_raw, wsum, w_norm, E);

    int gEdge = (E + 3) / 4;
    int gNode = (N + 3) / 4;
    for (int it = 0; it < 2; ++it) {
        hipMemsetAsync(m_node, 0, (size_t)2 * N * 64 * sizeof(float), stream);
        k_edge<<<gEdge, 256, 0, stream>>>(row, col, is_tie, w_norm,
                                          W_e1, b_e1, W_e2, b_e2, W_nn, b_nn,
                                          e_out, h_out, m_node, m_edge, E);
        k_node<<<gNode, 256, 0, stream>>>(is_cpl, deg, m_node, m_edge,
                                          W_g1, b_g1, W_g2, b_g2,
                                          W_ih, b_ih, W_hh, b_hh, h_out, N);
    }
}

// Round 3
// 2609.210 us; speedup vs baseline: 1.9490x; 1.9490x over previous
//
#include <hip/hip_runtime.h>
#include <hip/hip_bf16.h>
#include <math.h>

#define EPS 1e-6f

typedef short s16x8 __attribute__((ext_vector_type(8)));
typedef float f32x4 __attribute__((ext_vector_type(4)));

static __device__ __forceinline__ short f2bfs(float x) {
    __hip_bfloat16 h = __float2bfloat16(x);
    short s; __builtin_memcpy(&s, &h, 2); return s;
}

static __device__ __forceinline__ s16x8 load_a8(const float* p) {
    float4 u = *(const float4*)p;
    float4 v = *(const float4*)(p + 4);
    s16x8 a;
    a[0] = f2bfs(u.x); a[1] = f2bfs(u.y); a[2] = f2bfs(u.z); a[3] = f2bfs(u.w);
    a[4] = f2bfs(v.x); a[5] = f2bfs(v.y); a[6] = f2bfs(v.z); a[7] = f2bfs(v.w);
    return a;
}

// ---------------------------------------------------------------------------
// Precompute
// ---------------------------------------------------------------------------

__global__ __launch_bounds__(256) void k_flags(
    const int* __restrict__ row, const int* __restrict__ col,
    const int* __restrict__ is_tie, int* __restrict__ is_cpl,
    float* __restrict__ deg, int E)
{
    int e = blockIdx.x * 256 + threadIdx.x;
    if (e >= E) return;
    if (is_tie[e]) {
        atomicOr(&is_cpl[row[e]], 1);
        atomicOr(&is_cpl[col[e]], 1);
        atomicAdd(&deg[row[e]], 1.0f);
        atomicAdd(&deg[col[e]], 1.0f);
    }
}

__global__ __launch_bounds__(256) void k_wsum(
    const int* __restrict__ col, const int* __restrict__ is_tie,
    const float* __restrict__ attr, const int* __restrict__ is_cpl,
    float* __restrict__ wsum, int E)
{
    int e = blockIdx.x * 256 + threadIdx.x;
    if (e >= E) return;
    int c = col[e];
    if (!is_tie[e] && is_cpl[c]) {
        float X = fabsf(attr[(long long)e * 10 + 1]);
        atomicAdd(&wsum[c], 1.0f / sqrtf(X * X + EPS));
    }
}

__global__ __launch_bounds__(256) void k_compact(
    const int* __restrict__ col, const int* __restrict__ is_tie,
    const float* __restrict__ attr, const int* __restrict__ is_cpl,
    const float* __restrict__ wsum, int* __restrict__ cnt,
    int* __restrict__ tie_list, int* __restrict__ msg_list,
    float* __restrict__ msg_w, int E)
{
    int e = blockIdx.x * 256 + threadIdx.x;
    if (e >= E) return;
    if (is_tie[e]) {
        int p = atomicAdd(&cnt[0], 1);
        tie_list[p] = e;
    } else {
        int c = col[e];
        if (is_cpl[c]) {
            float X = fabsf(attr[(long long)e * 10 + 1]);
            float wr = 1.0f / sqrtf(X * X + EPS);
            int p = atomicAdd(&cnt[1], 1);
            msg_list[p] = e;
            msg_w[p] = wr / (wsum[c] + EPS);
        }
    }
}

// Pack W_e1 [192][128] -> W1t bf16 [128][192]; W_e2 [128][64] -> W2t [64][128]
__global__ __launch_bounds__(256) void k_pack(
    const float* __restrict__ W_e1, const float* __restrict__ W_e2,
    unsigned short* __restrict__ W1t, unsigned short* __restrict__ W2t)
{
    int i = blockIdx.x * 256 + threadIdx.x;
    if (i < 192 * 128) {
        int k = i >> 7, n = i & 127;
        W1t[n * 192 + k] = (unsigned short)f2bfs(W_e1[i]);
    }
    if (i < 128 * 64) {
        int k = i >> 6, n = i & 63;
        W2t[n * 128 + k] = (unsigned short)f2bfs(W_e2[i]);
    }
}

// ---------------------------------------------------------------------------
// Tie-edge MLP via MFMA: 16 edges per wave.
// GEMM1: X[16][192] @ W_e1 -> relu -> H1[16][128] (transposed to LDS bf16)
// GEMM2: H1 @ W_e2 -> e_ref[16][64]; residual + m_edge scatter.
// No __syncthreads: per-wave LDS slices only.
// ---------------------------------------------------------------------------

__global__ __launch_bounds__(256) void k_edge_mfma(
    const int* __restrict__ row, const int* __restrict__ col,
    const int* __restrict__ tie_list, const int* __restrict__ cnt,
    const unsigned short* __restrict__ W1t, const float* __restrict__ b_e1,
    const unsigned short* __restrict__ W2t, const float* __restrict__ b_e2,
    float* __restrict__ e_out, const float* __restrict__ h_out,
    float* __restrict__ m_edge)
{
    __shared__ unsigned short sH1[4][16 * 136];   // stride 136 bf16 = 272B rows
    int lane = threadIdx.x & 63, wv = threadIdx.x >> 6;
    int nt_cnt = cnt[0];
    int t = blockIdx.x * 4 + wv;
    if (t >= (nt_cnt + 15) >> 4) return;
    int r16 = lane & 15, hi = lane >> 4;

    // A-gather row (row index r16 of this tile)
    int tiA = t * 16 + r16;
    int edA = tie_list[min(tiA, nt_cnt - 1)];
    const float* seg0 = e_out + (long long)edA * 64;
    const float* seg1 = h_out + (long long)row[edA] * 64;
    const float* seg2 = h_out + (long long)col[edA] * 64;

    f32x4 acc[8];
    #pragma unroll
    for (int i = 0; i < 8; ++i) acc[i] = (f32x4){0.f, 0.f, 0.f, 0.f};

    #pragma unroll
    for (int s = 0; s < 6; ++s) {
        const float* base = (s < 2 ? seg0 : (s < 4 ? seg1 : seg2))
                            + (s & 1) * 32 + hi * 8;
        s16x8 a = load_a8(base);
        #pragma unroll
        for (int ct = 0; ct < 8; ++ct) {
            s16x8 b = *(const s16x8*)(W1t + (ct * 16 + r16) * 192 + s * 32 + hi * 8);
            acc[ct] = __builtin_amdgcn_mfma_f32_16x16x32_bf16(a, b, acc[ct], 0, 0, 0);
        }
    }

    // bias + relu + transpose through per-wave LDS (bf16)
    unsigned short* my = sH1[wv];
    #pragma unroll
    for (int ct = 0; ct < 8; ++ct) {
        float bc = b_e1[ct * 16 + r16];
        #pragma unroll
        for (int r = 0; r < 4; ++r) {
            float v = fmaxf(acc[ct][r] + bc, 0.f);
            my[(hi * 4 + r) * 136 + ct * 16 + r16] = (unsigned short)f2bfs(v);
        }
    }
    asm volatile("s_waitcnt lgkmcnt(0)" ::: "memory");
    __builtin_amdgcn_sched_barrier(0);

    f32x4 acc2[4];
    #pragma unroll
    for (int i = 0; i < 4; ++i) acc2[i] = (f32x4){0.f, 0.f, 0.f, 0.f};

    #pragma unroll
    for (int s = 0; s < 4; ++s) {
        s16x8 a2 = *(const s16x8*)(my + r16 * 136 + s * 32 + hi * 8);
        #pragma unroll
        for (int ct = 0; ct < 4; ++ct) {
            s16x8 b2 = *(const s16x8*)(W2t + (ct * 16 + r16) * 128 + s * 32 + hi * 8);
            acc2[ct] = __builtin_amdgcn_mfma_f32_16x16x32_bf16(a2, b2, acc2[ct], 0, 0, 0);
        }
    }

    // epilogue: rows owned by this lane are hi*4+r
    int ed2[4], rn2[4], cn2[4], ok2[4];
    #pragma unroll
    for (int r = 0; r < 4; ++r) {
        int ti = t * 16 + hi * 4 + r;
        ok2[r] = ti < nt_cnt;
        int e2 = tie_list[min(ti, nt_cnt - 1)];
        ed2[r] = e2; rn2[r] = row[e2]; cn2[r] = col[e2];
    }
    #pragma unroll
    for (int ct = 0; ct < 4; ++ct) {
        int colc = ct * 16 + r16;
        float b2 = b_e2[colc];
        #pragma unroll
        for (int r = 0; r < 4; ++r) {
            if (ok2[r]) {
                long long off = (long long)ed2[r] * 64 + colc;
                float en = e_out[off] + acc2[ct][r] + b2;
                e_out[off] = en;
                atomicAdd(&m_edge[(long long)rn2[r] * 64 + colc], en);
                atomicAdd(&m_edge[(long long)cn2[r] * 64 + colc], en);
            }
        }
    }
}

// ---------------------------------------------------------------------------
// Internal->coupling messages: W_nn staged in LDS, grid-stride over msg list
// ---------------------------------------------------------------------------

__global__ __launch_bounds__(256) void k_msg(
    const int* __restrict__ row, const int* __restrict__ col,
    const int* __restrict__ msg_list, const float* __restrict__ msg_w,
    const int* __restrict__ cnt,
    const float* __restrict__ W_nn, const float* __restrict__ b_nn,
    const float* __restrict__ h_out, float* __restrict__ m_node)
{
    __shared__ float sW[64 * 64];
    __shared__ float sx[4][64];
    int lane = threadIdx.x & 63, wv = threadIdx.x >> 6;
    for (int i = threadIdx.x; i < 64 * 64; i += 256) sW[i] = W_nn[i];
    __syncthreads();
    int cm = cnt[1];
    float bn = b_nn[lane];
    for (int i = blockIdx.x * 4 + wv; i < cm; i += gridDim.x * 4) {
        int ed = msg_list[i];
        float wn = msg_w[i];
        int c = col[ed];
        sx[wv][lane] = h_out[(long long)row[ed] * 64 + lane];
        float acc = bn;
        #pragma unroll 8
        for (int k = 0; k < 64; ++k)
            acc = fmaf(sx[wv][k], sW[k * 64 + lane], acc);
        atomicAdd(&m_node[(long long)c * 64 + lane], acc * wn);
    }
}

// ---------------------------------------------------------------------------
// Node update: gate MLP + GRU, ALL weights staged in LDS (152 KB)
// ---------------------------------------------------------------------------

__global__ __launch_bounds__(512) void k_node2(
    const int* __restrict__ is_cpl, const float* __restrict__ deg,
    const float* __restrict__ m_node, const float* __restrict__ m_edge,
    const float* __restrict__ W_g1, const float* __restrict__ b_g1,
    const float* __restrict__ W_g2, const float* __restrict__ b_g2,
    const float* __restrict__ W_ih, const float* __restrict__ b_ih,
    const float* __restrict__ W_hh, const float* __restrict__ b_hh,
    float* __restrict__ h_out, int N)
{
    __shared__ float sWg1[192 * 64];
    __shared__ float sWih[64 * 192];
    __shared__ float sWhh[64 * 192];
    __shared__ float sx[8][192];
    __shared__ float sm[8][64];
    int lane = threadIdx.x & 63, wv = threadIdx.x >> 6;
    for (int i = threadIdx.x; i < 12288; i += 512) {
        sWg1[i] = W_g1[i]; sWih[i] = W_ih[i]; sWhh[i] = W_hh[i];
    }
    __syncthreads();

    for (int n = blockIdx.x * 8 + wv; n < N; n += gridDim.x * 8) {
        if (!is_cpl[n]) continue;
        float dg = fmaxf(deg[n], 1.0f);
        float me = m_edge[(long long)n * 64 + lane] / dg;
        float mn = m_node[(long long)n * 64 + lane];
        float hv = h_out[(long long)n * 64 + lane];
        sx[wv][lane] = me;
        sx[wv][64 + lane] = mn;
        sx[wv][128 + lane] = hv;

        float a = b_g1[lane];
        #pragma unroll 8
        for (int k = 0; k < 192; ++k)
            a = fmaf(sx[wv][k], sWg1[k * 64 + lane], a);
        float p = fmaxf(a, 0.f) * W_g2[lane];
        #pragma unroll
        for (int off = 32; off; off >>= 1) p += __shfl_xor(p, off);
        float gate = 1.0f / (1.0f + expf(-(p + b_g2[0])));
        sm[wv][lane] = me + gate * mn;

        float gr = b_ih[lane], gz = b_ih[64 + lane], gn = b_ih[128 + lane];
        float hr = b_hh[lane], hz = b_hh[64 + lane], hn = b_hh[128 + lane];
        #pragma unroll 4
        for (int k = 0; k < 64; ++k) {
            float mk = sm[wv][k], hk = sx[wv][128 + k];
            gr = fmaf(mk, sWih[k * 192 + lane], gr);
            gz = fmaf(mk, sWih[k * 192 + 64 + lane], gz);
            gn = fmaf(mk, sWih[k * 192 + 128 + lane], gn);
            hr = fmaf(hk, sWhh[k * 192 + lane], hr);
            hz = fmaf(hk, sWhh[k * 192 + 64 + lane], hz);
            hn = fmaf(hk, sWhh[k * 192 + 128 + lane], hn);
        }
        float rg = 1.0f / (1.0f + expf(-(gr + hr)));
        float zg = 1.0f / (1.0f + expf(-(gz + hz)));
        float ng = tanhf(gn + rg * hn);
        h_out[(long long)n * 64 + lane] = (1.0f - zg) * ng + zg * hv;
    }
}

// ---------------------------------------------------------------------------
// Launch
// ---------------------------------------------------------------------------

extern "C" void kernel_launch(void* const* d_in, const int* in_sizes, int n_in,
                              void* d_out, int out_size, void* d_ws, size_t ws_size,
                              hipStream_t stream)
{
    const float* h      = (const float*)d_in[0];
    const float* e      = (const float*)d_in[1];
    const int*   eidx   = (const int*)d_in[2];
    const int*   is_tie = (const int*)d_in[3];
    const float* attr   = (const float*)d_in[4];
    const float* W_e1 = (const float*)d_in[5];  const float* b_e1 = (const float*)d_in[6];
    const float* W_e2 = (const float*)d_in[7];  const float* b_e2 = (const float*)d_in[8];
    const float* W_ih = (const float*)d_in[9];  const float* b_ih = (const float*)d_in[10];
    const float* W_hh = (const float*)d_in[11]; const float* b_hh = (const float*)d_in[12];
    const float* W_nn = (const float*)d_in[13]; const float* b_nn = (const float*)d_in[14];
    const float* W_g1 = (const float*)d_in[15]; const float* b_g1 = (const float*)d_in[16];
    const float* W_g2 = (const float*)d_in[17]; const float* b_g2 = (const float*)d_in[18];

    int N = in_sizes[0] / 64;
    int E = in_sizes[2] / 2;
    const int* row = eidx;
    const int* col = eidx + E;

    float* h_out = (float*)d_out;
    float* e_out = h_out + (long long)N * 64;

    // workspace: is_cpl[N] | wsum[N] | deg[N] | cnt[4] | tie_list[E] |
    //            msg_list[E] | msg_w[E] | W1t[24576]u16 | W2t[8192]u16 |
    //            m_node[N*64] | m_edge[N*64]
    float* ws = (float*)d_ws;
    int*   is_cpl   = (int*)ws;
    float* wsum     = ws + N;
    float* deg      = ws + 2LL * N;
    int*   cnt      = (int*)(ws + 3LL * N);
    int*   tie_list = cnt + 4;
    int*   msg_list = tie_list + E;
    float* msg_w    = (float*)(msg_list + E);
    unsigned short* W1t = (unsigned short*)(msg_w + E);
    unsigned short* W2t = W1t + 24576;
    float* m_node = (float*)(W2t + 8192);
    float* m_edge = m_node + (long long)N * 64;

    hipMemsetAsync(ws, 0, ((size_t)3 * N + 4) * sizeof(float), stream);
    hipMemcpyAsync(h_out, h, (size_t)N * 64 * sizeof(float),
                   hipMemcpyDeviceToDevice, stream);
    hipMemcpyAsync(e_out, e, (size_t)E * 64 * sizeof(float),
                   hipMemcpyDeviceToDevice, stream);

    int gE = (E + 255) / 256;
    k_flags  <<<gE, 256, 0, stream>>>(row, col, is_tie, is_cpl, deg, E);
    k_wsum   <<<gE, 256, 0, stream>>>(col, is_tie, attr, is_cpl, wsum, E);
    k_pack   <<<96, 256, 0, stream>>>(W_e1, W_e2, W1t, W2t);
    k_compact<<<gE, 256, 0, stream>>>(col, is_tie, attr, is_cpl, wsum, cnt,
                                      tie_list, msg_list, msg_w, E);

    int gEdge = ((E + 15) / 16 + 3) / 4;   // worst-case tiles, waves self-exit
    for (int it = 0; it < 2; ++it) {
        hipMemsetAsync(m_node, 0, (size_t)2 * N * 64 * sizeof(float), stream);
        k_edge_mfma<<<gEdge, 256, 0, stream>>>(row, col, tie_list, cnt,
                                               W1t, b_e1, W2t, b_e2,
                                               e_out, h_out, m_edge);
        k_msg <<<2048, 256, 0, stream>>>(row, col, msg_list, msg_w, cnt,
                                         W_nn, b_nn, h_out, m_node);
        k_node2<<<256, 512, 0, stream>>>(is_cpl, deg, m_node, m_edge,
                                         W_g1, b_g1, W_g2, b_g2,
                                         W_ih, b_ih, W_hh, b_hh, h_out, N);
    }
}

// Round 6
// 2105.341 us; speedup vs baseline: 2.4154x; 1.2393x over previous
//
#include <hip/hip_runtime.h>
#include <hip/hip_bf16.h>
#include <math.h>

#define EPS 1e-6f

typedef short s16x8 __attribute__((ext_vector_type(8)));
typedef float f32x4 __attribute__((ext_vector_type(4)));

static __device__ __forceinline__ short f2bfs(float x) {
    __hip_bfloat16 h = __float2bfloat16(x);
    short s; __builtin_memcpy(&s, &h, 2); return s;
}

static __device__ __forceinline__ s16x8 load_a8(const float* p) {
    float4 u = *(const float4*)p;
    float4 v = *(const float4*)(p + 4);
    s16x8 a;
    a[0] = f2bfs(u.x); a[1] = f2bfs(u.y); a[2] = f2bfs(u.z); a[3] = f2bfs(u.w);
    a[4] = f2bfs(v.x); a[5] = f2bfs(v.y); a[6] = f2bfs(v.z); a[7] = f2bfs(v.w);
    return a;
}

static __device__ __forceinline__ void load8f(const float* p, float* f) {
    float4 u = *(const float4*)p;
    float4 v = *(const float4*)(p + 4);
    f[0]=u.x; f[1]=u.y; f[2]=u.z; f[3]=u.w;
    f[4]=v.x; f[5]=v.y; f[6]=v.z; f[7]=v.w;
}

static __device__ __forceinline__ s16x8 cvt8(const float* f) {
    s16x8 a;
    #pragma unroll
    for (int j = 0; j < 8; ++j) a[j] = f2bfs(f[j]);
    return a;
}

// ---------------------------------------------------------------------------
// Precompute
// ---------------------------------------------------------------------------

__global__ __launch_bounds__(256) void k_flags(
    const int* __restrict__ row, const int* __restrict__ col,
    const int* __restrict__ is_tie, int* __restrict__ is_cpl,
    float* __restrict__ deg, int E)
{
    int e = blockIdx.x * 256 + threadIdx.x;
    if (e >= E) return;
    if (is_tie[e]) {
        atomicOr(&is_cpl[row[e]], 1);
        atomicOr(&is_cpl[col[e]], 1);
        atomicAdd(&deg[row[e]], 1.0f);
        atomicAdd(&deg[col[e]], 1.0f);
    }
}

__global__ __launch_bounds__(256) void k_wsum(
    const int* __restrict__ col, const int* __restrict__ is_tie,
    const float* __restrict__ attr, const int* __restrict__ is_cpl,
    float* __restrict__ wsum, int E)
{
    int e = blockIdx.x * 256 + threadIdx.x;
    if (e >= E) return;
    int c = col[e];
    if (!is_tie[e] && is_cpl[c]) {
        float X = fabsf(attr[(long long)e * 10 + 1]);
        atomicAdd(&wsum[c], 1.0f / sqrtf(X * X + EPS));
    }
}

__global__ __launch_bounds__(256) void k_compact(
    const int* __restrict__ col, const int* __restrict__ is_tie,
    const float* __restrict__ attr, const int* __restrict__ is_cpl,
    const float* __restrict__ wsum, int* __restrict__ cnt,
    int* __restrict__ tie_list, int* __restrict__ msg_list,
    float* __restrict__ msg_w, int E)
{
    int e = blockIdx.x * 256 + threadIdx.x;
    if (e >= E) return;
    if (is_tie[e]) {
        int p = atomicAdd(&cnt[0], 1);
        tie_list[p] = e;
    } else {
        int c = col[e];
        if (is_cpl[c]) {
            float X = fabsf(attr[(long long)e * 10 + 1]);
            float wr = 1.0f / sqrtf(X * X + EPS);
            int p = atomicAdd(&cnt[1], 1);
            msg_list[p] = e;
            msg_w[p] = wr / (wsum[c] + EPS);
        }
    }
}

__global__ __launch_bounds__(256) void k_cpl(
    const int* __restrict__ is_cpl, int* __restrict__ cnt,
    int* __restrict__ cpl_list, int N)
{
    int n = blockIdx.x * 256 + threadIdx.x;
    if (n < N && is_cpl[n]) cpl_list[atomicAdd(&cnt[2], 1)] = n;
}

// Pack all weights to bf16, transposed to [col][k] (B-fragment friendly)
__global__ __launch_bounds__(256) void k_pack(
    const float* __restrict__ W_e1, const float* __restrict__ W_e2,
    const float* __restrict__ W_g1, const float* __restrict__ W_ih,
    const float* __restrict__ W_hh, const float* __restrict__ W_nn,
    unsigned short* __restrict__ W1t, unsigned short* __restrict__ W2t,
    unsigned short* __restrict__ Wg1t, unsigned short* __restrict__ Wiht,
    unsigned short* __restrict__ Whht, unsigned short* __restrict__ Wnnt)
{
    int i = blockIdx.x * 256 + threadIdx.x;
    if (i < 192 * 128) { int k = i >> 7, n = i & 127; W1t[n * 192 + k] = (unsigned short)f2bfs(W_e1[i]); }
    if (i < 128 * 64)  { int k = i >> 6, n = i & 63;  W2t[n * 128 + k] = (unsigned short)f2bfs(W_e2[i]); }
    if (i < 192 * 64)  { int k = i >> 6, n = i & 63;  Wg1t[n * 192 + k] = (unsigned short)f2bfs(W_g1[i]); }
    if (i < 64 * 192)  { int k = i / 192, n = i % 192;
                         Wiht[n * 64 + k] = (unsigned short)f2bfs(W_ih[i]);
                         Whht[n * 64 + k] = (unsigned short)f2bfs(W_hh[i]); }
    if (i < 64 * 64)   { int k = i >> 6, n = i & 63;  Wnnt[n * 64 + k] = (unsigned short)f2bfs(W_nn[i]); }
}

// ---------------------------------------------------------------------------
// Tie-edge MLP via MFMA: 16 edges per wave
// ---------------------------------------------------------------------------

__global__ __launch_bounds__(256) void k_edge_mfma(
    const int* __restrict__ row, const int* __restrict__ col,
    const int* __restrict__ tie_list, const int* __restrict__ cnt,
    const unsigned short* __restrict__ W1t, const float* __restrict__ b_e1,
    const unsigned short* __restrict__ W2t, const float* __restrict__ b_e2,
    float* __restrict__ e_out, const float* __restrict__ h_out,
    float* __restrict__ m_edge)
{
    __shared__ unsigned short sH1[4][16 * 136];
    int lane = threadIdx.x & 63, wv = threadIdx.x >> 6;
    int nt_cnt = cnt[0];
    int t = blockIdx.x * 4 + wv;
    if (t >= (nt_cnt + 15) >> 4) return;
    int r16 = lane & 15, hi = lane >> 4;

    int tiA = t * 16 + r16;
    int edA = tie_list[min(tiA, nt_cnt - 1)];
    const float* seg0 = e_out + (long long)edA * 64;
    const float* seg1 = h_out + (long long)row[edA] * 64;
    const float* seg2 = h_out + (long long)col[edA] * 64;

    f32x4 acc[8];
    #pragma unroll
    for (int i = 0; i < 8; ++i) acc[i] = (f32x4){0.f, 0.f, 0.f, 0.f};

    #pragma unroll
    for (int s = 0; s < 6; ++s) {
        const float* base = (s < 2 ? seg0 : (s < 4 ? seg1 : seg2))
                            + (s & 1) * 32 + hi * 8;
        s16x8 a = load_a8(base);
        #pragma unroll
        for (int ct = 0; ct < 8; ++ct) {
            s16x8 b = *(const s16x8*)(W1t + (ct * 16 + r16) * 192 + s * 32 + hi * 8);
            acc[ct] = __builtin_amdgcn_mfma_f32_16x16x32_bf16(a, b, acc[ct], 0, 0, 0);
        }
    }

    unsigned short* my = sH1[wv];
    #pragma unroll
    for (int ct = 0; ct < 8; ++ct) {
        float bc = b_e1[ct * 16 + r16];
        #pragma unroll
        for (int r = 0; r < 4; ++r) {
            float v = fmaxf(acc[ct][r] + bc, 0.f);
            my[(hi * 4 + r) * 136 + ct * 16 + r16] = (unsigned short)f2bfs(v);
        }
    }
    asm volatile("s_waitcnt lgkmcnt(0)" ::: "memory");
    __builtin_amdgcn_sched_barrier(0);

    f32x4 acc2[4];
    #pragma unroll
    for (int i = 0; i < 4; ++i) acc2[i] = (f32x4){0.f, 0.f, 0.f, 0.f};

    #pragma unroll
    for (int s = 0; s < 4; ++s) {
        s16x8 a2 = *(const s16x8*)(my + r16 * 136 + s * 32 + hi * 8);
        #pragma unroll
        for (int ct = 0; ct < 4; ++ct) {
            s16x8 b2 = *(const s16x8*)(W2t + (ct * 16 + r16) * 128 + s * 32 + hi * 8);
            acc2[ct] = __builtin_amdgcn_mfma_f32_16x16x32_bf16(a2, b2, acc2[ct], 0, 0, 0);
        }
    }

    int ed2[4], rn2[4], cn2[4], ok2[4];
    #pragma unroll
    for (int r = 0; r < 4; ++r) {
        int ti = t * 16 + hi * 4 + r;
        ok2[r] = ti < nt_cnt;
        int e2 = tie_list[min(ti, nt_cnt - 1)];
        ed2[r] = e2; rn2[r] = row[e2]; cn2[r] = col[e2];
    }
    #pragma unroll
    for (int ct = 0; ct < 4; ++ct) {
        int colc = ct * 16 + r16;
        float b2 = b_e2[colc];
        #pragma unroll
        for (int r = 0; r < 4; ++r) {
            if (ok2[r]) {
                long long off = (long long)ed2[r] * 64 + colc;
                float en = e_out[off] + acc2[ct][r] + b2;
                e_out[off] = en;
                atomicAdd(&m_edge[(long long)rn2[r] * 64 + colc], en);
                atomicAdd(&m_edge[(long long)cn2[r] * 64 + colc], en);
            }
        }
    }
}

// ---------------------------------------------------------------------------
// Internal->coupling messages via MFMA: 16 edges per wave
// ---------------------------------------------------------------------------

__global__ __launch_bounds__(256) void k_msg_mfma(
    const int* __restrict__ row, const int* __restrict__ col,
    const int* __restrict__ msg_list, const float* __restrict__ msg_w,
    const int* __restrict__ cnt,
    const unsigned short* __restrict__ Wnnt, const float* __restrict__ b_nn,
    const float* __restrict__ h_out, float* __restrict__ m_node)
{
    int lane = threadIdx.x & 63, wv = threadIdx.x >> 6;
    int cm = cnt[1];
    int t = blockIdx.x * 4 + wv;
    if (t >= (cm + 15) >> 4) return;
    int r16 = lane & 15, hi = lane >> 4;

    int tiA = t * 16 + r16;
    int edA = msg_list[min(tiA, cm - 1)];
    const float* ph = h_out + (long long)row[edA] * 64;
    float f[16];
    load8f(ph + hi * 8, f);
    load8f(ph + 32 + hi * 8, f + 8);
    s16x8 a0 = cvt8(f), a1 = cvt8(f + 8);

    f32x4 acc[4];
    #pragma unroll
    for (int i = 0; i < 4; ++i) acc[i] = (f32x4){0.f, 0.f, 0.f, 0.f};
    #pragma unroll
    for (int ct = 0; ct < 4; ++ct) {
        s16x8 b0 = *(const s16x8*)(Wnnt + (ct * 16 + r16) * 64 + hi * 8);
        s16x8 b1 = *(const s16x8*)(Wnnt + (ct * 16 + r16) * 64 + 32 + hi * 8);
        acc[ct] = __builtin_amdgcn_mfma_f32_16x16x32_bf16(a0, b0, acc[ct], 0, 0, 0);
        acc[ct] = __builtin_amdgcn_mfma_f32_16x16x32_bf16(a1, b1, acc[ct], 0, 0, 0);
    }

    int cn[4], ok[4]; float wn[4];
    #pragma unroll
    for (int r = 0; r < 4; ++r) {
        int ti = t * 16 + hi * 4 + r;
        ok[r] = ti < cm;
        int i2 = min(ti, cm - 1);
        cn[r] = col[msg_list[i2]];
        wn[r] = msg_w[i2];
    }
    int c16 = lane & 15;
    #pragma unroll
    for (int ct = 0; ct < 4; ++ct) {
        int colc = ct * 16 + c16;
        float bn = b_nn[colc];
        #pragma unroll
        for (int r = 0; r < 4; ++r) {
            if (ok[r])
                atomicAdd(&m_node[(long long)cn[r] * 64 + colc],
                          (acc[ct][r] + bn) * wn[r]);
        }
    }
}

// ---------------------------------------------------------------------------
// Node update via MFMA: 16 coupling nodes per wave.
// ---------------------------------------------------------------------------

__global__ __launch_bounds__(256) void k_node_mfma(
    const int* __restrict__ cpl_list, const int* __restrict__ cnt,
    const float* __restrict__ deg,
    const float* __restrict__ m_node, const float* __restrict__ m_edge,
    const unsigned short* __restrict__ Wg1t, const float* __restrict__ b_g1,
    const float* __restrict__ W_g2, const float* __restrict__ b_g2,
    const unsigned short* __restrict__ Wiht, const float* __restrict__ b_ih,
    const unsigned short* __restrict__ Whht, const float* __restrict__ b_hh,
    float* __restrict__ h_out)
{
    __shared__ float sg[4][16];
    int lane = threadIdx.x & 63, wv = threadIdx.x >> 6;
    int nc = cnt[2];
    int t = blockIdx.x * 4 + wv;
    if (t >= (nc + 15) >> 4) return;
    int r16 = lane & 15, hi = lane >> 4;

    int tiA = t * 16 + r16;
    int node = cpl_list[min(tiA, nc - 1)];
    float inv_dg = 1.0f / fmaxf(deg[node], 1.0f);

    float me[16], mn[16], tmp[16];
    load8f(m_edge + (long long)node * 64 + hi * 8, me);
    load8f(m_edge + (long long)node * 64 + 32 + hi * 8, me + 8);
    load8f(m_node + (long long)node * 64 + hi * 8, mn);
    load8f(m_node + (long long)node * 64 + 32 + hi * 8, mn + 8);
    load8f(h_out + (long long)node * 64 + hi * 8, tmp);
    load8f(h_out + (long long)node * 64 + 32 + hi * 8, tmp + 8);
    #pragma unroll
    for (int j = 0; j < 16; ++j) me[j] *= inv_dg;

    s16x8 afr[6];
    afr[0] = cvt8(me); afr[1] = cvt8(me + 8);
    afr[2] = cvt8(mn); afr[3] = cvt8(mn + 8);
    afr[4] = cvt8(tmp); afr[5] = cvt8(tmp + 8);

    // GEMM1: gate hidden layer
    f32x4 accg[4];
    #pragma unroll
    for (int i = 0; i < 4; ++i) accg[i] = (f32x4){0.f, 0.f, 0.f, 0.f};
    #pragma unroll
    for (int s = 0; s < 6; ++s) {
        #pragma unroll
        for (int ct = 0; ct < 4; ++ct) {
            s16x8 b = *(const s16x8*)(Wg1t + (ct * 16 + r16) * 192 + s * 32 + hi * 8);
            accg[ct] = __builtin_amdgcn_mfma_f32_16x16x32_bf16(afr[s], b, accg[ct], 0, 0, 0);
        }
    }

    // gate: relu, dot with W_g2, reduce over 64 cols
    float p[4];
    #pragma unroll
    for (int r = 0; r < 4; ++r) {
        float s = 0.f;
        #pragma unroll
        for (int ct = 0; ct < 4; ++ct) {
            int colc = ct * 16 + r16;
            s += fmaxf(accg[ct][r] + b_g1[colc], 0.f) * W_g2[colc];
        }
        p[r] = s;
    }
    #pragma unroll
    for (int off = 1; off < 16; off <<= 1) {
        #pragma unroll
        for (int r = 0; r < 4; ++r) p[r] += __shfl_xor(p[r], off);
    }
    float bg2 = b_g2[0];
    if ((lane & 15) == 0) {
        #pragma unroll
        for (int r = 0; r < 4; ++r)
            sg[wv][hi * 4 + r] = 1.0f / (1.0f + expf(-(p[r] + bg2)));
    }
    asm volatile("s_waitcnt lgkmcnt(0)" ::: "memory");
    __builtin_amdgcn_sched_barrier(0);
    float g = sg[wv][r16];

    // m = me + gate*mn (f32, lane-local — same layout as A fragments)
    #pragma unroll
    for (int j = 0; j < 16; ++j) me[j] = fmaf(g, mn[j], me[j]);
    s16x8 am0 = cvt8(me), am1 = cvt8(me + 8);

    // GEMM2: gi = m @ W_ih, gh = hv @ W_hh
    f32x4 ai[12], ah[12];
    #pragma unroll
    for (int i = 0; i < 12; ++i) {
        ai[i] = (f32x4){0.f, 0.f, 0.f, 0.f};
        ah[i] = (f32x4){0.f, 0.f, 0.f, 0.f};
    }
    #pragma unroll
    for (int ct = 0; ct < 12; ++ct) {
        const unsigned short* bi = Wiht + (ct * 16 + r16) * 64;
        const unsigned short* bh = Whht + (ct * 16 + r16) * 64;
        s16x8 b0 = *(const s16x8*)(bi + hi * 8);
        s16x8 b1 = *(const s16x8*)(bi + 32 + hi * 8);
        s16x8 c0 = *(const s16x8*)(bh + hi * 8);
        s16x8 c1 = *(const s16x8*)(bh + 32 + hi * 8);
        ai[ct] = __builtin_amdgcn_mfma_f32_16x16x32_bf16(am0, b0, ai[ct], 0, 0, 0);
        ai[ct] = __builtin_amdgcn_mfma_f32_16x16x32_bf16(am1, b1, ai[ct], 0, 0, 0);
        ah[ct] = __builtin_amdgcn_mfma_f32_16x16x32_bf16(afr[4], c0, ah[ct], 0, 0, 0);
        ah[ct] = __builtin_amdgcn_mfma_f32_16x16x32_bf16(afr[5], c1, ah[ct], 0, 0, 0);
    }

    // epilogue: lane-local GRU math in C layout
    int nd[4], ok[4];
    #pragma unroll
    for (int r = 0; r < 4; ++r) {
        int ti = t * 16 + hi * 4 + r;
        ok[r] = ti < nc;
        nd[r] = cpl_list[min(ti, nc - 1)];
    }
    int c16 = lane & 15;
    #pragma unroll
    for (int r = 0; r < 4; ++r) {
        if (!ok[r]) continue;
        #pragma unroll
        for (int cb = 0; cb < 4; ++cb) {
            int colc = cb * 16 + c16;
            float rg = 1.0f / (1.0f + expf(-(ai[cb][r] + b_ih[colc] + ah[cb][r] + b_hh[colc])));
            float zg = 1.0f / (1.0f + expf(-(ai[cb + 4][r] + b_ih[64 + colc] + ah[cb + 4][r] + b_hh[64 + colc])));
            float ng = tanhf(ai[cb + 8][r] + b_ih[128 + colc]
                             + rg * (ah[cb + 8][r] + b_hh[128 + colc]));
            long long off = (long long)nd[r] * 64 + colc;
            float hvv = h_out[off];
            h_out[off] = (1.0f - zg) * ng + zg * hvv;
        }
    }
}

// ---------------------------------------------------------------------------
// Launch
// ---------------------------------------------------------------------------

extern "C" void kernel_launch(void* const* d_in, const int* in_sizes, int n_in,
                              void* d_out, int out_size, void* d_ws, size_t ws_size,
                              hipStream_t stream)
{
    const float* h      = (const float*)d_in[0];
    const float* e      = (const float*)d_in[1];
    const int*   eidx   = (const int*)d_in[2];
    const int*   is_tie = (const int*)d_in[3];
    const float* attr   = (const float*)d_in[4];
    const float* W_e1 = (const float*)d_in[5];  const float* b_e1 = (const float*)d_in[6];
    const float* W_e2 = (const float*)d_in[7];  const float* b_e2 = (const float*)d_in[8];
    const float* W_ih = (const float*)d_in[9];  const float* b_ih = (const float*)d_in[10];
    const float* W_hh = (const float*)d_in[11]; const float* b_hh = (const float*)d_in[12];
    const float* W_nn = (const float*)d_in[13]; const float* b_nn = (const float*)d_in[14];
    const float* W_g1 = (const float*)d_in[15]; const float* b_g1 = (const float*)d_in[16];
    const float* W_g2 = (const float*)d_in[17]; const float* b_g2 = (const float*)d_in[18];

    int N = in_sizes[0] / 64;
    int E = in_sizes[2] / 2;
    const int* row = eidx;
    const int* col = eidx + E;

    float* h_out = (float*)d_out;
    float* e_out = h_out + (long long)N * 64;

    // workspace layout
    float* ws = (float*)d_ws;
    int*   is_cpl   = (int*)ws;                    // N
    float* wsum     = ws + N;                      // N
    float* deg      = ws + 2LL * N;                // N
    int*   cnt      = (int*)(ws + 3LL * N);        // 4
    int*   tie_list = cnt + 4;                     // E
    int*   msg_list = tie_list + E;                // E
    float* msg_w    = (float*)(msg_list + E);      // E
    int*   cpl_list = (int*)(msg_w + E);           // N
    unsigned short* W1t  = (unsigned short*)(cpl_list + N);  // 24576
    unsigned short* W2t  = W1t + 24576;            // 8192
    unsigned short* Wg1t = W2t + 8192;             // 12288
    unsigned short* Wiht = Wg1t + 12288;           // 12288
    unsigned short* Whht = Wiht + 12288;           // 12288
    unsigned short* Wnnt = Whht + 12288;           // 4096
    float* m_node = (float*)(Wnnt + 4096);         // N*64
    float* m_edge = m_node + (long long)N * 64;    // N*64

    hipMemsetAsync(ws, 0, ((size_t)3 * N + 4) * sizeof(float), stream);
    hipMemcpyAsync(h_out, h, (size_t)N * 64 * sizeof(float),
                   hipMemcpyDeviceToDevice, stream);
    hipMemcpyAsync(e_out, e, (size_t)E * 64 * sizeof(float),
                   hipMemcpyDeviceToDevice, stream);

    int gE = (E + 255) / 256;
    int gN = (N + 255) / 256;
    k_flags  <<<gE, 256, 0, stream>>>(row, col, is_tie, is_cpl, deg, E);
    k_wsum   <<<gE, 256, 0, stream>>>(col, is_tie, attr, is_cpl, wsum, E);
    k_pack   <<<96, 256, 0, stream>>>(W_e1, W_e2, W_g1, W_ih, W_hh, W_nn,
                                      W1t, W2t, Wg1t, Wiht, Whht, Wnnt);
    k_compact<<<gE, 256, 0, stream>>>(col, is_tie, attr, is_cpl, wsum, cnt,
                                      tie_list, msg_list, msg_w, E);
    k_cpl    <<<gN, 256, 0, stream>>>(is_cpl, cnt, cpl_list, N);

    int gEdge = ((E + 15) / 16 + 3) / 4;       // worst case, waves self-exit
    int gMsg  = gEdge;
    int gNode = ((N + 15) / 16 + 3) / 4;
    for (int it = 0; it < 2; ++it) {
        hipMemsetAsync(m_node, 0, (size_t)2 * N * 64 * sizeof(float), stream);
        k_edge_mfma<<<gEdge, 256, 0, stream>>>(row, col, tie_list, cnt,
                                               W1t, b_e1, W2t, b_e2,
                                               e_out, h_out, m_edge);
        k_msg_mfma <<<gMsg, 256, 0, stream>>>(row, col, msg_list, msg_w, cnt,
                                              Wnnt, b_nn, h_out, m_node);
        k_node_mfma<<<gNode, 256, 0, stream>>>(cpl_list, cnt, deg,
                                               m_node, m_edge,
                                               Wg1t, b_g1, W_g2, b_g2,
                                               Wiht, b_ih, Whht, b_hh, h_out);
    }
}